// Round 5
// baseline (263.847 us; speedup 1.0000x reference)
//
#include <hip/hip_runtime.h>
#include <hip/hip_bf16.h>
#include <math.h>

#define CC   128          // channels
#define HWN  16384        // H*W
#define EE   4            // experts
#define RR   64           // rank
#define TP   64           // pixels per tile in k_experts
#define NT   (HWN / TP)   // 256 tiles per batch image

typedef __attribute__((ext_vector_type(8))) short short8;
typedef __attribute__((ext_vector_type(4))) float f32x4;

// ---------- helpers ----------
__device__ __forceinline__ unsigned short f2bf(float f) {
    __hip_bfloat16 h = __float2bfloat16(f);
    return *reinterpret_cast<unsigned short*>(&h);
}
__device__ __forceinline__ unsigned pk2bf(float lo, float hi) {
    return (unsigned)f2bf(lo) | ((unsigned)f2bf(hi) << 16);
}
__device__ __forceinline__ float gelu_exact(float v) {
    return 0.5f * v * (1.0f + erff(v * 0.7071067811865475f));
}
__device__ __forceinline__ float silu_f(float v) {
    return v / (1.0f + expf(-v));
}

// ======================================================================
// k_prep blocks:
//   [0,2048): conv+pack for (b, ch-pair dpr, 32-row band):
//       - 3x3 highpass conv + gelu-mean + mean on x, shfl-FREE:
//         lane owns cols {2l,2l+1} of BOTH channels (float2 loads);
//         l/r neighbors via direct L1-hit scalar loads. Row loop body =
//         6 independent global loads -> VALU -> 1 store: deep pipelining.
//       - bf16 pack of x AND sh rows for the band -> scratch inside out
//       - per-band fe0/pooled partials (4 per image-ch) -> summed in k_route
//   then: weight convert / proj-fold / mlp warm (light blocks).
// Scratch word (b,d,p) inside out: d<64 -> x ch(2d,2d+1); d>=64 -> sh.
// Race-free vs k_experts: each expert tile overwrites exactly the words
// it read.
// ======================================================================
#define PREP_CONV 2048
#define PREP_WCV  (PREP_CONV + 128)
#define PREP_WF   (PREP_WCV + 128)
#define PREP_GRID (PREP_WF + 48)
__global__ __launch_bounds__(256) void k_prep(
    const float* __restrict__ x,   const float* __restrict__ sh,
    const float* __restrict__ proj,
    const float* __restrict__ ew0, const float* __restrict__ ew1,
    const float* __restrict__ ew2,
    const float* __restrict__ mw1, const float* __restrict__ mw2,
    const float* __restrict__ gw,  const float* __restrict__ fgw,
    float* __restrict__ fe0p, float* __restrict__ poolp,
    unsigned short* __restrict__ projb, unsigned short* __restrict__ w0b,
    unsigned short* __restrict__ w1b,   unsigned short* __restrict__ w2pb,
    float* __restrict__ outw, float* __restrict__ dummy)
{
    __shared__ float wr[4][4];   // [wave][sgA,sxA,sgB,sxB]
    const int bx = blockIdx.x, tid = threadIdx.x;

    if (bx < PREP_CONV) {
        const int b    = bx >> 8;
        const int dpr  = (bx >> 2) & 63;    // channel pair 0..63
        const int band = bx & 3;            // 32-row band 0..3
        const int ln   = tid & 63;
        const int wv   = tid >> 6;          // wave = 8-row stream
        const int c0   = ln << 1;           // cols 2l, 2l+1
        const int r0   = band * 32 + wv * 8;

        const float* srcA = x + ((size_t)(b * CC + 2 * dpr)) * HWN;
        const float* srcB = srcA + HWN;
        unsigned* dst = (unsigned*)outw + ((size_t)(b * CC + dpr)) * HWN;

        const bool le = (c0 == 0), re = (c0 == 126);
        const int cl = le ? 0 : c0 - 1;      // clamped (value zeroed below)
        const int cr = re ? 127 : c0 + 2;

        const float2 z2 = {0.f, 0.f};
        float2 tA, tB, mA, mB;
        float tlA, trA, tlB, trB, mlA, mrA, mlB, mrB;
        if (r0 > 0) {
            const float* rA = srcA + (size_t)(r0 - 1) * 128;
            const float* rB = srcB + (size_t)(r0 - 1) * 128;
            tA = *(const float2*)(rA + c0);
            tB = *(const float2*)(rB + c0);
            tlA = le ? 0.f : rA[cl]; trA = re ? 0.f : rA[cr];
            tlB = le ? 0.f : rB[cl]; trB = re ? 0.f : rB[cr];
        } else { tA = z2; tB = z2; tlA = trA = tlB = trB = 0.f; }
        {
            const float* rA = srcA + (size_t)r0 * 128;
            const float* rB = srcB + (size_t)r0 * 128;
            mA = *(const float2*)(rA + c0);
            mB = *(const float2*)(rB + c0);
            mlA = le ? 0.f : rA[cl]; mrA = re ? 0.f : rA[cr];
            mlB = le ? 0.f : rB[cl]; mrB = re ? 0.f : rB[cr];
        }

        float sgA = 0.f, sxA = 0.f, sgB = 0.f, sxB = 0.f;
        #pragma unroll
        for (int g = 0; g < 8; ++g) {
            const int gr = r0 + g;
            float2 bA, bB; float blA, brA, blB, brB;
            if (gr + 1 < 128) {
                const float* rA = srcA + (size_t)(gr + 1) * 128;
                const float* rB = srcB + (size_t)(gr + 1) * 128;
                bA = *(const float2*)(rA + c0);
                bB = *(const float2*)(rB + c0);
                blA = le ? 0.f : rA[cl]; brA = re ? 0.f : rA[cr];
                blB = le ? 0.f : rB[cl]; brB = re ? 0.f : rB[cr];
            } else { bA = z2; bB = z2; blA = brA = blB = brB = 0.f; }
            {
                float s8 = ((tlA + tA.x) + (tA.y + mlA)) + ((mA.y + blA) + (bA.x + bA.y));
                sgA += gelu_exact(8.f * mA.x - s8);
                s8 = ((tA.x + tA.y) + (trA + mA.x)) + ((mrA + bA.x) + (bA.y + brA));
                sgA += gelu_exact(8.f * mA.y - s8);
                sxA += mA.x + mA.y;
            }
            {
                float s8 = ((tlB + tB.x) + (tB.y + mlB)) + ((mB.y + blB) + (bB.x + bB.y));
                sgB += gelu_exact(8.f * mB.x - s8);
                s8 = ((tB.x + tB.y) + (trB + mB.x)) + ((mrB + bB.x) + (bB.y + brB));
                sgB += gelu_exact(8.f * mB.y - s8);
                sxB += mB.x + mB.y;
            }
            uint2 w;
            w.x = pk2bf(mA.x, mB.x);
            w.y = pk2bf(mA.y, mB.y);
            *(uint2*)(dst + (size_t)gr * 128 + c0) = w;
            tA = mA; tlA = mlA; trA = mrA; mA = bA; mlA = blA; mrA = brA;
            tB = mB; tlB = mlB; trB = mrB; mB = bB; mlB = blB; mrB = brB;
        }
        #pragma unroll
        for (int off = 32; off; off >>= 1) {
            sgA += __shfl_xor(sgA, off, 64); sxA += __shfl_xor(sxA, off, 64);
            sgB += __shfl_xor(sgB, off, 64); sxB += __shfl_xor(sxB, off, 64);
        }
        if (ln == 0) { wr[wv][0] = sgA; wr[wv][1] = sxA; wr[wv][2] = sgB; wr[wv][3] = sxB; }
        // ---- sh pack for same (b, dpr, band): pure streaming ----
        {
            const float4* a4  = (const float4*)(sh + ((size_t)(b * CC + 2 * dpr)) * HWN + band * 4096);
            const float4* c4p = (const float4*)(sh + ((size_t)(b * CC + 2 * dpr + 1)) * HWN + band * 4096);
            uint4* dsts = (uint4*)((unsigned*)outw + ((size_t)(b * CC + 64 + dpr)) * HWN + band * 4096);
            #pragma unroll
            for (int it = 0; it < 4; ++it) {
                const int i = it * 256 + tid;
                float4 a = a4[i], c = c4p[i];
                uint4 w;
                w.x = pk2bf(a.x, c.x); w.y = pk2bf(a.y, c.y);
                w.z = pk2bf(a.z, c.z); w.w = pk2bf(a.w, c.w);
                dsts[i] = w;
            }
        }
        __syncthreads();
        if (tid < 4) {
            float s = (wr[0][tid] + wr[1][tid]) + (wr[2][tid] + wr[3][tid]);
            s *= (1.f / 16384.f);
            const int o = band * 1024 + b * CC + 2 * dpr;
            if (tid == 0) fe0p [o]     = s;
            if (tid == 1) poolp[o]     = s;
            if (tid == 2) fe0p [o + 1] = s;
            if (tid == 3) poolp[o + 1] = s;
        }
    } else if (bx < PREP_WCV) {
        // ---- convert proj/w0/w1 to bf16 ----
        int i = (bx - PREP_CONV) * 256 + tid;      // 0..32767
        if (i < CC * CC) projb[i] = f2bf(proj[i]);
        w0b[i] = f2bf(ew0[i]);
        w1b[i] = f2bf(ew1[i]);
    } else if (bx < PREP_WF) {
        // ---- fold proj into w2 -> bf16 ----
        const int bb = bx - PREP_WCV;              // 0..127
        const int e  = bb >> 5;
        const int d  = ((bb & 31) << 2) + (tid >> 6);
        const int r  = tid & 63;
        const float* pr = proj + d * CC;
        const float* wz = ew2 + (size_t)e * CC * RR + r;
        float a0 = 0.f, a1 = 0.f, a2 = 0.f, a3 = 0.f;
        for (int c = 0; c < CC; c += 4) {
            a0 += pr[c + 0] * wz[(c + 0) * RR];
            a1 += pr[c + 1] * wz[(c + 1) * RR];
            a2 += pr[c + 2] * wz[(c + 2) * RR];
            a3 += pr[c + 3] * wz[(c + 3) * RR];
        }
        w2pb[(e * CC + d) * RR + r] = f2bf((a0 + a1) + (a2 + a3));
    } else {
        // ---- warm MLP weights + gates (48 blocks) ----
        const int i = (bx - PREP_WF) * 256 + tid;    // 0..12287
        float s = 0.f;
        for (int j = i; j < CC * 2 * CC; j += 48 * 256) s += mw1[j] + mw2[j];
        if (i < CC * EE) s += gw[i] + fgw[i];
        if (s == 12345.678f) dummy[1] = s;
    }
}

// ---------- routing: MLP + softmax + top-2 (one block per batch) ----------
__global__ __launch_bounds__(256) void k_route(
    const float* __restrict__ fe0p, const float* __restrict__ poolp,
    const float* __restrict__ w1, const float* __restrict__ b1,
    const float* __restrict__ w2, const float* __restrict__ b2,
    const float* __restrict__ gw, const float* __restrict__ fgw,
    float* __restrict__ gates, float* __restrict__ gsum)
{
    const int b = blockIdx.x, tid = threadIdx.x;
    __shared__ float hh[256];
    __shared__ float fe[128];
    __shared__ float lg[4];
    {
        const float* f0 = fe0p + b * CC;
        float a[8];
        #pragma unroll
        for (int j = 0; j < 8; ++j) a[j] = 0.f;
        for (int c = 0; c < CC; c += 8)
            #pragma unroll
            for (int j = 0; j < 8; ++j) {
                const int cc = c + j;
                float v = (f0[cc] + f0[1024 + cc]) + (f0[2048 + cc] + f0[3072 + cc]);
                a[j] += v * w1[cc * 256 + tid];
            }
        float acc = b1[tid] + ((a[0]+a[1]) + (a[2]+a[3])) + ((a[4]+a[5]) + (a[6]+a[7]));
        hh[tid] = gelu_exact(acc);
    }
    __syncthreads();
    if (tid < 128) {
        float a[8];
        #pragma unroll
        for (int j = 0; j < 8; ++j) a[j] = 0.f;
        for (int c = 0; c < 256; c += 8)
            #pragma unroll
            for (int j = 0; j < 8; ++j) a[j] += hh[c + j] * w2[(c + j) * 128 + tid];
        fe[tid] = b2[tid] + ((a[0]+a[1]) + (a[2]+a[3])) + ((a[4]+a[5]) + (a[6]+a[7]));
    }
    __syncthreads();
    if (tid < EE) {
        const float* pl = poolp + b * CC;
        float l0=0.f, l1=0.f, l2=0.f, l3=0.f;
        for (int c = 0; c < CC; c += 4) {
            float p0 = (pl[c+0] + pl[1024+c+0]) + (pl[2048+c+0] + pl[3072+c+0]);
            float p1 = (pl[c+1] + pl[1024+c+1]) + (pl[2048+c+1] + pl[3072+c+1]);
            float p2 = (pl[c+2] + pl[1024+c+2]) + (pl[2048+c+2] + pl[3072+c+2]);
            float p3 = (pl[c+3] + pl[1024+c+3]) + (pl[2048+c+3] + pl[3072+c+3]);
            l0 += p0 * gw[(c+0) * EE + tid] + fe[c+0] * fgw[(c+0) * EE + tid];
            l1 += p1 * gw[(c+1) * EE + tid] + fe[c+1] * fgw[(c+1) * EE + tid];
            l2 += p2 * gw[(c+2) * EE + tid] + fe[c+2] * fgw[(c+2) * EE + tid];
            l3 += p3 * gw[(c+3) * EE + tid] + fe[c+3] * fgw[(c+3) * EE + tid];
        }
        lg[tid] = (l0 + l1) + (l2 + l3);
    }
    __syncthreads();
    if (tid == 0) {
        float mx = fmaxf(fmaxf(lg[0], lg[1]), fmaxf(lg[2], lg[3]));
        float sc[EE]; float ssum = 0.f;
        for (int e = 0; e < EE; ++e) { sc[e] = expf(lg[e] - mx); ssum += sc[e]; }
        float inv = 1.f / ssum;
        for (int e = 0; e < EE; ++e) sc[e] *= inv;
        int i1 = 0;
        for (int e = 1; e < EE; ++e) if (sc[e] > sc[i1]) i1 = e;
        int i2 = -1;
        for (int e = 0; e < EE; ++e) {
            if (e == i1) continue;
            if (i2 < 0 || sc[e] > sc[i2]) i2 = e;
        }
        for (int e = 0; e < EE; ++e)
            gates[b * EE + e] = (e == i1) ? sc[i1] : (e == i2 ? sc[i2] : 0.f);
        gsum[b] = sc[i1] + sc[i2];
    }
}

// ======================================================================
// k_experts: experts + combine + proj, MFMA bf16, XOR-swizzled LDS
//   staging reads pre-packed bf16 words from out (written by k_prep):
//   word (b,d,p): d<64 -> x channels (2d,2d+1); d>=64 -> sh channels.
//   Tile (b,P) reads only words {*, p in P} and overwrites exactly them.
// ======================================================================
__global__ __launch_bounds__(256, 4) void k_experts(
    const unsigned short* __restrict__ w0b, const unsigned short* __restrict__ w1b,
    const unsigned short* __restrict__ w2pb, const unsigned short* __restrict__ projb,
    const float* __restrict__ gates, const float* __restrict__ gsum,
    float* __restrict__ out)
{
    __shared__ __align__(16) unsigned short xs [TP * CC];  // 16384 B
    __shared__ __align__(16) unsigned short shs[TP * CC];  // 16384 B
    __shared__ __align__(16) unsigned short us [TP * RR];  //  8192 B
    const int tid  = threadIdx.x;
    const int b    = blockIdx.x >> 8;
    const int tile = blockIdx.x & (NT - 1);
    const int p0   = tile * TP;

    // ---- stage x/sh from packed scratch: coalesced uint loads, no cvt ----
    {
        const unsigned* wsrc = (const unsigned*)out + ((size_t)b * CC) * HWN + p0;
        const int p  = tid & 63;
        const int qh = tid >> 6;                    // 0..3
        #pragma unroll
        for (int it = 0; it < 4; ++it) {
            const int q  = it * 4 + qh;             // chunk 0..15 (8 channels each)
            const int sw = p * CC + ((q ^ (p & 15)) << 3);
            const unsigned* px_ = wsrc + (size_t)(q * 4) * HWN + p;
            const unsigned* ps_ = wsrc + (size_t)(64 + q * 4) * HWN + p;
            uint4 wx, wh;
            wx.x = px_[0]; wx.y = px_[HWN]; wx.z = px_[2 * HWN]; wx.w = px_[3 * HWN];
            wh.x = ps_[0]; wh.y = ps_[HWN]; wh.z = ps_[2 * HWN]; wh.w = ps_[3 * HWN];
            *(uint4*)&xs [sw] = wx;
            *(uint4*)&shs[sw] = wh;
        }
    }
    __syncthreads();

    const int wv = tid >> 6;        // wave 0..3
    const int ln = tid & 63;
    const int lp = ln & 15;         // m/n index within 16-tile
    const int lq = ln >> 4;         // quad

    f32x4 acc[2][4];                // [d-tile][p-tile], d in [wv*32, wv*32+32)
    #pragma unroll
    for (int i = 0; i < 2; ++i)
        #pragma unroll
        for (int j = 0; j < 4; ++j) acc[i][j] = (f32x4){0.f, 0.f, 0.f, 0.f};

    // ---- proj stage: acc = proj @ x  (K=128) ----
    {
        const int d0 = wv * 32;
        #pragma unroll
        for (int ks = 0; ks < 4; ++ks) {
            const int k0 = ks * 32 + lq * 8;
            const int ch = ks * 4 + lq;
            short8 a0 = *(const short8*)&projb[(d0 +      lp) * CC + k0];
            short8 a1 = *(const short8*)&projb[(d0 + 16 + lp) * CC + k0];
            #pragma unroll
            for (int pt = 0; pt < 4; ++pt) {
                short8 bf = *(const short8*)&xs[(pt * 16 + lp) * CC + ((ch ^ lp) << 3)];
                acc[0][pt] = __builtin_amdgcn_mfma_f32_16x16x32_bf16(a0, bf, acc[0][pt], 0, 0, 0);
                acc[1][pt] = __builtin_amdgcn_mfma_f32_16x16x32_bf16(a1, bf, acc[1][pt], 0, 0, 0);
            }
        }
        const float gs = gsum[b];
        #pragma unroll
        for (int i = 0; i < 2; ++i)
            #pragma unroll
            for (int j = 0; j < 4; ++j) acc[i][j] *= gs;
    }

    // ---- experts ----
    for (int e = 0; e < EE; ++e) {
        const float ge = gates[b * EE + e];
        if (ge == 0.f) continue;                       // block-uniform

        // stage A: a = W0 @ x, g = W1 @ sh  (rows wv*16..wv*16+16, K=128)
        f32x4 af[4], gf[4];
        #pragma unroll
        for (int pt = 0; pt < 4; ++pt) { af[pt] = (f32x4){0.f,0.f,0.f,0.f}; gf[pt] = (f32x4){0.f,0.f,0.f,0.f}; }
        const unsigned short* w0e = w0b + (size_t)(e * RR + wv * 16) * CC;
        const unsigned short* w1e = w1b + (size_t)(e * RR + wv * 16) * CC;
        #pragma unroll
        for (int ks = 0; ks < 4; ++ks) {
            const int k0 = ks * 32 + lq * 8;
            const int ch = ks * 4 + lq;
            short8 a0 = *(const short8*)&w0e[lp * CC + k0];
            short8 a1 = *(const short8*)&w1e[lp * CC + k0];
            #pragma unroll
            for (int pt = 0; pt < 4; ++pt) {
                const int sw = (pt * 16 + lp) * CC + ((ch ^ lp) << 3);
                short8 bx = *(const short8*)&xs [sw];
                short8 bs = *(const short8*)&shs[sw];
                af[pt] = __builtin_amdgcn_mfma_f32_16x16x32_bf16(a0, bx, af[pt], 0, 0, 0);
                gf[pt] = __builtin_amdgcn_mfma_f32_16x16x32_bf16(a1, bs, gf[pt], 0, 0, 0);
            }
        }
        __syncthreads();   // prev expert's us fully consumed
        // u = ge * a * silu(g) -> bf16 -> us (C layout row r = wv*16+lq*4+i)
        #pragma unroll
        for (int pt = 0; pt < 4; ++pt) {
            unsigned short t[4];
            #pragma unroll
            for (int i = 0; i < 4; ++i)
                t[i] = f2bf(ge * af[pt][i] * silu_f(gf[pt][i]));
            const int p = pt * 16 + lp;
            const int addr = p * RR + (((wv * 2 + (lq >> 1)) ^ (lp & 7)) << 3) + ((lq & 1) << 2);
            *(uint2*)&us[addr] = *(uint2*)t;
        }
        __syncthreads();   // us visible to all waves
        // stage B: acc += W2p[e] @ u   (K=64)
        const unsigned short* w2e = w2pb + (size_t)(e * CC + wv * 32) * RR;
        #pragma unroll
        for (int ks = 0; ks < 2; ++ks) {
            const int k0 = ks * 32 + lq * 8;
            const int ch = ks * 4 + lq;
            short8 a0 = *(const short8*)&w2e[lp * RR + k0];
            short8 a1 = *(const short8*)&w2e[(16 + lp) * RR + k0];
            #pragma unroll
            for (int pt = 0; pt < 4; ++pt) {
                short8 bu = *(const short8*)&us[(pt * 16 + lp) * RR + ((ch ^ (lp & 7)) << 3)];
                acc[0][pt] = __builtin_amdgcn_mfma_f32_16x16x32_bf16(a0, bu, acc[0][pt], 0, 0, 0);
                acc[1][pt] = __builtin_amdgcn_mfma_f32_16x16x32_bf16(a1, bu, acc[1][pt], 0, 0, 0);
            }
        }
    }

    // ---- store: lane holds (d = wv*32 + dt*16 + lq*4 + i, p = p0 + pt*16 + lp) ----
    {
        const int d0 = wv * 32;
        #pragma unroll
        for (int dt = 0; dt < 2; ++dt)
            #pragma unroll
            for (int pt = 0; pt < 4; ++pt) {
                float* ob = out + ((size_t)(b * CC + d0 + dt * 16 + lq * 4)) * HWN + p0 + pt * 16 + lp;
                #pragma unroll
                for (int i = 0; i < 4; ++i)
                    ob[(size_t)i * HWN] = acc[dt][pt][i];
            }
    }
}

// ---------- launch ----------
extern "C" void kernel_launch(void* const* d_in, const int* in_sizes, int n_in,
                              void* d_out, int out_size, void* d_ws, size_t ws_size,
                              hipStream_t stream) {
    const float* x    = (const float*)d_in[0];
    const float* shr  = (const float*)d_in[1];
    const float* mw1  = (const float*)d_in[2];
    const float* mb1  = (const float*)d_in[3];
    const float* mw2  = (const float*)d_in[4];
    const float* mb2  = (const float*)d_in[5];
    const float* gw   = (const float*)d_in[6];
    const float* fgw  = (const float*)d_in[7];
    const float* ew0  = (const float*)d_in[8];
    const float* ew1  = (const float*)d_in[9];
    const float* ew2  = (const float*)d_in[10];
    const float* pw   = (const float*)d_in[11];
    float* out = (float*)d_out;

    float* ws     = (float*)d_ws;
    float* fe0p   = ws + 0;        // 4096 f (4 band partials)
    float* poolp  = ws + 4096;     // 4096 f
    float* gates  = ws + 8192;     // 32 f
    float* gsum   = ws + 8224;     // 8 f
    float* dummy  = ws + 8232;     // 8 f (+pad to 8256)
    unsigned short* projb = (unsigned short*)(ws + 8256);   // 16384 us
    unsigned short* w0b   = projb + 16384;                  // 32768 us
    unsigned short* w1b   = w0b + 32768;                    // 32768 us
    unsigned short* w2pb  = w1b + 32768;                    // 32768 us

    k_prep   <<<PREP_GRID, 256, 0, stream>>>(x, shr, pw, ew0, ew1, ew2, mw1, mw2,
                                             gw, fgw, fe0p, poolp, projb, w0b, w1b, w2pb,
                                             out, dummy);
    k_route  <<<8,         256, 0, stream>>>(fe0p, poolp, mw1, mb1, mw2, mb2, gw, fgw, gates, gsum);
    k_experts<<<8 * NT,    256, 0, stream>>>(w0b, w1b, w2pb, projb, gates, gsum, out);
}